// Round 8
// baseline (93.078 us; speedup 1.0000x reference)
//
#include <hip/hip_runtime.h>

#define B_ 4
#define N_ 512
#define D_ 768
#define A_ 128

typedef short bf16x8 __attribute__((ext_vector_type(8)));
typedef ushort u16x8 __attribute__((ext_vector_type(8)));
typedef float f32x4 __attribute__((ext_vector_type(4)));

__device__ __forceinline__ ushort f2h(float x) {  // f32 -> bf16 bits, RNE
  uint u = __builtin_bit_cast(uint, x);
  return (ushort)((u + 0x7fffu + ((u >> 16) & 1u)) >> 16);
}
__device__ __forceinline__ float h2f(ushort h) {
  uint u = ((uint)h) << 16;
  return __builtin_bit_cast(float, u);
}
__device__ __forceinline__ bf16x8 ld8(const ushort* p) {
  return *(const bf16x8*)p;
}
#define MFMA(a, b, c) __builtin_amdgcn_mfma_f32_16x16x32_bf16(a, b, c, 0, 0, 0)

// ---------------------------------------------------------------------------
// k0: fused prep.
//  blocks 0..767: split M into bf16 hi/lo, Mr [2048][768] row-major (k1 A)
//                 and Mt [4][768][512] transposed (k3 B).
//  blocks 768..863: Wt[c][k] = (c<128?W1:W2)[k][c%128] bf16 hi/lo [256][768].
// ---------------------------------------------------------------------------
__global__ __launch_bounds__(256) void k0_prep(
    const float* __restrict__ M, const float* __restrict__ W1,
    const float* __restrict__ W2, ushort* __restrict__ Mr_h,
    ushort* __restrict__ Mr_l, ushort* __restrict__ Mt_h,
    ushort* __restrict__ Mt_l, ushort* __restrict__ Wt_h,
    ushort* __restrict__ Wt_l) {
  __shared__ ushort lds_h[64][40];
  __shared__ ushort lds_l[64][40];
  const int t = threadIdx.x;
  const int bid = blockIdx.x;
  if (bid < 768) {  // ---- M part ----
    const int dq = bid % 12;
    const int rest = bid / 12;
    const int d0 = dq * 64;
    const int n0 = (rest & 15) * 32;
    const int b = rest >> 4;
    const int n = t >> 3;          // 0..31
    const int dg = (t & 7) * 8;    // 0..56
    const size_t roff = ((size_t)(b * N_ + n0 + n)) * D_ + d0 + dg;
    const float4 v0 = *(const float4*)(M + roff);
    const float4 v1 = *(const float4*)(M + roff + 4);
    const float x[8] = {v0.x, v0.y, v0.z, v0.w, v1.x, v1.y, v1.z, v1.w};
    u16x8 vh, vl;
#pragma unroll
    for (int e = 0; e < 8; ++e) {
      ushort h = f2h(x[e]);
      ushort l = f2h(x[e] - h2f(h));
      vh[e] = h;
      vl[e] = l;
      lds_h[dg + e][n] = h;
      lds_l[dg + e][n] = l;
    }
    *(u16x8*)(Mr_h + roff) = vh;
    *(u16x8*)(Mr_l + roff) = vl;
    __syncthreads();
    const int dd = t >> 2;          // 0..63
    const int ng = (t & 3) * 8;     // 0..24
    const size_t toff = ((size_t)b * D_ + d0 + dd) * N_ + n0 + ng;
    *(u16x8*)(Mt_h + toff) = *(const u16x8*)(&lds_h[dd][ng]);
    *(u16x8*)(Mt_l + toff) = *(const u16x8*)(&lds_l[dd][ng]);
  } else {  // ---- W part ----
    const int c = t;
    const int k0 = (bid - 768) * 8;
    const float* __restrict__ Wp = (c < A_) ? W1 : W2;
    const int cc = c & (A_ - 1);
    u16x8 vh, vl;
#pragma unroll
    for (int e = 0; e < 8; ++e) {
      float x = Wp[(size_t)(k0 + e) * A_ + cc];
      ushort h = f2h(x);
      vh[e] = h;
      vl[e] = f2h(x - h2f(h));
    }
    *(u16x8*)(Wt_h + (size_t)c * D_ + k0) = vh;
    *(u16x8*)(Wt_l + (size_t)c * D_ + k0) = vl;
  }
}

// ---------------------------------------------------------------------------
// k1: ws12[2048][256] = M @ [W1|W2], +bias, *2log2(e).  MFMA 16x16x32 bf16,
// 3-pass split (Ah@Bh + Ah@Bl + Al@Bh). 1 wave/block, tile 32x32, register-
// prefetch pipeline. w1 = cols 0..127, w2 = cols 128..255.
// ---------------------------------------------------------------------------
__global__ __launch_bounds__(64) void k1_mfma(
    const ushort* __restrict__ Mr_h, const ushort* __restrict__ Mr_l,
    const ushort* __restrict__ Wt_h, const ushort* __restrict__ Wt_l,
    const float* __restrict__ b1, const float* __restrict__ b2,
    float* __restrict__ ws12) {
  const int l = threadIdx.x;
  const int r = l & 15, g = l >> 4;
  const int row0 = blockIdx.x * 32;
  const int cb = blockIdx.y * 32;
  const size_t oA = (size_t)(row0 + r) * D_ + g * 8;
  const size_t oA2 = oA + (size_t)16 * D_;
  const size_t oB = (size_t)(cb + r) * D_ + g * 8;
  const size_t oB2 = oB + (size_t)16 * D_;
  f32x4 acc[2][2] = {};
  bf16x8 A[2][4], Bv[2][4];
#define K1LOAD(s, k0)                                                        \
  A[s][0] = ld8(Mr_h + oA + (k0));  A[s][1] = ld8(Mr_h + oA2 + (k0));        \
  A[s][2] = ld8(Mr_l + oA + (k0));  A[s][3] = ld8(Mr_l + oA2 + (k0));        \
  Bv[s][0] = ld8(Wt_h + oB + (k0)); Bv[s][1] = ld8(Wt_h + oB2 + (k0));       \
  Bv[s][2] = ld8(Wt_l + oB + (k0)); Bv[s][3] = ld8(Wt_l + oB2 + (k0));
#define K1MM(s)                                                              \
  acc[0][0] = MFMA(A[s][0], Bv[s][0], acc[0][0]);                            \
  acc[0][0] = MFMA(A[s][0], Bv[s][2], acc[0][0]);                            \
  acc[0][0] = MFMA(A[s][2], Bv[s][0], acc[0][0]);                            \
  acc[0][1] = MFMA(A[s][0], Bv[s][1], acc[0][1]);                            \
  acc[0][1] = MFMA(A[s][0], Bv[s][3], acc[0][1]);                            \
  acc[0][1] = MFMA(A[s][2], Bv[s][1], acc[0][1]);                            \
  acc[1][0] = MFMA(A[s][1], Bv[s][0], acc[1][0]);                            \
  acc[1][0] = MFMA(A[s][1], Bv[s][2], acc[1][0]);                            \
  acc[1][0] = MFMA(A[s][3], Bv[s][0], acc[1][0]);                            \
  acc[1][1] = MFMA(A[s][1], Bv[s][1], acc[1][1]);                            \
  acc[1][1] = MFMA(A[s][1], Bv[s][3], acc[1][1]);                            \
  acc[1][1] = MFMA(A[s][3], Bv[s][1], acc[1][1]);
  K1LOAD(0, 0)
#pragma unroll
  for (int kt = 0; kt < 24; ++kt) {
    if (kt & 1) {
      if (kt + 1 < 24) { K1LOAD(0, (kt + 1) * 32) }
      K1MM(1)
    } else {
      if (kt + 1 < 24) { K1LOAD(1, (kt + 1) * 32) }
      K1MM(0)
    }
  }
#undef K1LOAD
#undef K1MM
  const float SC = 2.8853900817779268f;  // 2*log2(e): e^{2x} = 2^{SC*x}
#pragma unroll
  for (int fj = 0; fj < 2; ++fj) {
    const int c = cb + fj * 16 + r;
    const float bias = (c < A_) ? b1[c] : b2[c - A_];
#pragma unroll
    for (int fi = 0; fi < 2; ++fi)
#pragma unroll
      for (int rr = 0; rr < 4; ++rr) {
        const int row = row0 + fi * 16 + g * 4 + rr;
        ws12[(size_t)row * 256 + c] = (acc[fi][fj][rr] + bias) * SC;
      }
  }
}

// ---------------------------------------------------------------------------
// k2 v7: DENSE trans-bound scores. Block = 4 waves = 4 rows; 8 j-tiles of 64.
// w2 double-buffered in LDS [a][j] (pad 65, lane-indexed reads conflict-
// free), staged cooperatively with async split: global loads issued BEFORE
// compute, LDS writes AFTER (T14). Per element exactly
// {add, exp2, add, rcp, fmac} -- trans-pipe-bound (~13.7us floor dense).
// Wave owns its full row: scores in s[8] regs, softmax = 8 regs + butterfly.
// Masked -> f32.min -> exp underflow 0 (ref match); all-masked -> 1/512.
// ---------------------------------------------------------------------------
__global__ __launch_bounds__(256) void k2_scores(
    const float* __restrict__ ws12, const int* __restrict__ mask,
    const float* __restrict__ vw, ushort* __restrict__ ah,
    ushort* __restrict__ al) {
  __shared__ float l_w2[2][A_][65];  // 66.6 KB
  __shared__ float l_w1[4][A_];
  __shared__ float l_v2[A_];
  const int t = threadIdx.x;
  const int lane = t & 63;
  const int w = t >> 6;
  const int i0 = blockIdx.x * 4;
  const int b = i0 >> 9;
  const int i = i0 + w;

  for (int k = t; k < 4 * A_; k += 256)
    l_w1[k >> 7][k & 127] = ws12[(size_t)(i0 + (k >> 7)) * 256 + (k & 127)];
  if (t < A_) l_v2[t] = -2.f * vw[t];
  float vs = vw[lane] + vw[64 + lane];  // Vsum via butterfly
#pragma unroll
  for (int off = 32; off; off >>= 1) vs += __shfl_xor(vs, off);

  const float* __restrict__ w2src = ws12 + (size_t)b * N_ * 256 + A_;
  float4 st[8];  // staging regs: tile = 64 j x 128 a = 2048 f4 / 256 thr

#define STAGE_LOAD(jt)                                                      \
  {                                                                         \
    const int j0 = (jt) * 64;                                               \
    _Pragma("unroll") for (int k = 0; k < 8; ++k) {                         \
      const int f = t + k * 256;                                            \
      const int jj = f >> 5;                                                \
      const int a4 = (f & 31) * 4;                                          \
      st[k] = *(const float4*)(w2src + (size_t)(j0 + jj) * 256 + a4);       \
    }                                                                       \
  }
#define STAGE_WRITE(bf)                                                     \
  {                                                                         \
    _Pragma("unroll") for (int k = 0; k < 8; ++k) {                         \
      const int f = t + k * 256;                                            \
      const int jj = f >> 5;                                                \
      const int a4 = (f & 31) * 4;                                          \
      l_w2[bf][a4 + 0][jj] = st[k].x;                                       \
      l_w2[bf][a4 + 1][jj] = st[k].y;                                       \
      l_w2[bf][a4 + 2][jj] = st[k].z;                                       \
      l_w2[bf][a4 + 3][jj] = st[k].w;                                       \
    }                                                                       \
  }

  STAGE_LOAD(0)
  STAGE_WRITE(0)
  __syncthreads();

  const float4* __restrict__ w1q = (const float4*)&l_w1[w][0];
  const float4* __restrict__ v2q = (const float4*)&l_v2[0];
  const float NEG = -3.402823466e38f;  // np.finfo(f32).min
  float s[8];
#pragma unroll
  for (int jt = 0; jt < 8; ++jt) {
    if (jt + 1 < 8) STAGE_LOAD(jt + 1)          // issue early (T14)
    const int mk = mask[(size_t)i * N_ + jt * 64 + lane];
    const float(*wb)[65] = l_w2[jt & 1];
    float acc = vs;
#pragma unroll 4
    for (int c = 0; c < 32; ++c) {
      const float4 wa = w1q[c];
      const float4 vv = v2q[c];
      const float x0 = wb[c * 4 + 0][lane];
      const float x1 = wb[c * 4 + 1][lane];
      const float x2 = wb[c * 4 + 2][lane];
      const float x3 = wb[c * 4 + 3][lane];
      const float e0 = __builtin_amdgcn_exp2f(wa.x + x0);
      const float e1 = __builtin_amdgcn_exp2f(wa.y + x1);
      const float e2 = __builtin_amdgcn_exp2f(wa.z + x2);
      const float e3 = __builtin_amdgcn_exp2f(wa.w + x3);
      acc = fmaf(vv.x, __builtin_amdgcn_rcpf(e0 + 1.f), acc);
      acc = fmaf(vv.y, __builtin_amdgcn_rcpf(e1 + 1.f), acc);
      acc = fmaf(vv.z, __builtin_amdgcn_rcpf(e2 + 1.f), acc);
      acc = fmaf(vv.w, __builtin_amdgcn_rcpf(e3 + 1.f), acc);
    }
    s[jt] = mk ? acc : NEG;
    if (jt + 1 < 8) { STAGE_WRITE((jt + 1) & 1) }  // write late (T14)
    __syncthreads();
  }
#undef STAGE_LOAD
#undef STAGE_WRITE

  // fused softmax: 8 regs x 64 lanes = full row per wave
  float rmax = s[0];
#pragma unroll
  for (int jt = 1; jt < 8; ++jt) rmax = fmaxf(rmax, s[jt]);
#pragma unroll
  for (int off = 32; off; off >>= 1) rmax = fmaxf(rmax, __shfl_xor(rmax, off));
  const float L2E = 1.4426950408889634f;
  float psum = 0.f;
#pragma unroll
  for (int jt = 0; jt < 8; ++jt) {
    // all-masked row: s-rmax = 0 -> 1 -> uniform 1/512 (ref match);
    // masked in live row: (NEG-rmax)*L2E -> -inf -> exp2 = 0 exactly.
    s[jt] = __builtin_amdgcn_exp2f((s[jt] - rmax) * L2E);
    psum += s[jt];
  }
#pragma unroll
  for (int off = 32; off; off >>= 1) psum += __shfl_xor(psum, off);
  const float inv = __builtin_amdgcn_rcpf(psum);
#pragma unroll
  for (int jt = 0; jt < 8; ++jt) {
    const float pv = s[jt] * inv;
    const ushort hh = f2h(pv);
    ah[(size_t)i * N_ + jt * 64 + lane] = hh;
    al[(size_t)i * N_ + jt * 64 + lane] = f2h(pv - h2f(hh));
  }
}

// ---------------------------------------------------------------------------
// k3: out[b] = attn[b] @ M[b].  MFMA 16x16x32 bf16, 3-pass split, register-
// prefetch pipeline. 1 wave/block, tile 32 i x 32 d (1536 blocks, 6 w/CU).
// ---------------------------------------------------------------------------
__global__ __launch_bounds__(64) void k3_mfma(
    const ushort* __restrict__ ah, const ushort* __restrict__ al,
    const ushort* __restrict__ Mt_h, const ushort* __restrict__ Mt_l,
    float* __restrict__ out) {
  const int l = threadIdx.x;
  const int r = l & 15, g = l >> 4;
  const int row0 = blockIdx.x * 32;    // global row b*N+i
  const int d0 = blockIdx.y * 32;
  const int b = row0 >> 9;
  const ushort* __restrict__ Bh = Mt_h + (size_t)b * D_ * N_;
  const ushort* __restrict__ Bl = Mt_l + (size_t)b * D_ * N_;
  const size_t oA = (size_t)(row0 + r) * N_ + g * 8;
  const size_t oA2 = oA + (size_t)16 * N_;
  const size_t oB = (size_t)(d0 + r) * N_ + g * 8;
  const size_t oB2 = oB + (size_t)16 * N_;
  f32x4 acc[2][2] = {};
  bf16x8 A[2][4], Bv[2][4];
#define K3LOAD(s, j0)                                                        \
  A[s][0] = ld8(ah + oA + (j0));  A[s][1] = ld8(ah + oA2 + (j0));            \
  A[s][2] = ld8(al + oA + (j0));  A[s][3] = ld8(al + oA2 + (j0));            \
  Bv[s][0] = ld8(Bh + oB + (j0)); Bv[s][1] = ld8(Bh + oB2 + (j0));           \
  Bv[s][2] = ld8(Bl + oB + (j0)); Bv[s][3] = ld8(Bl + oB2 + (j0));
#define K3MM(s)                                                              \
  acc[0][0] = MFMA(A[s][0], Bv[s][0], acc[0][0]);                            \
  acc[0][0] = MFMA(A[s][0], Bv[s][2], acc[0][0]);                            \
  acc[0][0] = MFMA(A[s][2], Bv[s][0], acc[0][0]);                            \
  acc[0][1] = MFMA(A[s][0], Bv[s][1], acc[0][1]);                            \
  acc[0][1] = MFMA(A[s][0], Bv[s][3], acc[0][1]);                            \
  acc[0][1] = MFMA(A[s][2], Bv[s][1], acc[0][1]);                            \
  acc[1][0] = MFMA(A[s][1], Bv[s][0], acc[1][0]);                            \
  acc[1][0] = MFMA(A[s][1], Bv[s][2], acc[1][0]);                            \
  acc[1][0] = MFMA(A[s][3], Bv[s][0], acc[1][0]);                            \
  acc[1][1] = MFMA(A[s][1], Bv[s][1], acc[1][1]);                            \
  acc[1][1] = MFMA(A[s][1], Bv[s][3], acc[1][1]);                            \
  acc[1][1] = MFMA(A[s][3], Bv[s][1], acc[1][1]);
  K3LOAD(0, 0)
#pragma unroll
  for (int kt = 0; kt < 16; ++kt) {
    if (kt & 1) {
      if (kt + 1 < 16) { K3LOAD(0, (kt + 1) * 32) }
      K3MM(1)
    } else {
      if (kt + 1 < 16) { K3LOAD(1, (kt + 1) * 32) }
      K3MM(0)
    }
  }
#undef K3LOAD
#undef K3MM
#pragma unroll
  for (int fi = 0; fi < 2; ++fi)
#pragma unroll
    for (int fd = 0; fd < 2; ++fd)
#pragma unroll
      for (int rr = 0; rr < 4; ++rr)
        out[(size_t)(row0 + fi * 16 + g * 4 + rr) * D_ + d0 + fd * 16 + r] =
            acc[fi][fd][rr];
}

extern "C" void kernel_launch(void* const* d_in, const int* in_sizes, int n_in,
                              void* d_out, int out_size, void* d_ws,
                              size_t ws_size, hipStream_t stream) {
  const float* M = (const float*)d_in[0];
  const int* mask = (const int*)d_in[1];
  const float* W1 = (const float*)d_in[2];
  const float* b1 = (const float*)d_in[3];
  const float* W2 = (const float*)d_in[4];
  const float* b2 = (const float*)d_in[5];
  const float* vw = (const float*)d_in[6];
  float* out = (float*)d_out;

  // workspace carve-up: 18.75 MB total
  float* ws12 = (float*)d_ws;                     // [2048][256] f32   2 MB
  ushort* ah = (ushort*)(ws12 + 2048 * 256);      // [2048][512] bf16  2 MB
  ushort* al = ah + 2048 * N_;                    //                   2 MB
  ushort* Mr_h = al + 2048 * N_;                  // [2048][768] bf16  3 MB
  ushort* Mr_l = Mr_h + 2048 * D_;                //                   3 MB
  ushort* Mt_h = Mr_l + 2048 * D_;                // [4][768][512]     3 MB
  ushort* Mt_l = Mt_h + 2048 * D_;                //                   3 MB
  ushort* Wt_h = Mt_l + 2048 * D_;                // [256][768] bf16   .375
  ushort* Wt_l = Wt_h + 256 * D_;                 //                   .375

  k0_prep<<<864, 256, 0, stream>>>(M, W1, W2, Mr_h, Mr_l, Mt_h, Mt_l,
                                   Wt_h, Wt_l);
  k1_mfma<<<dim3(2048 / 32, 8), 64, 0, stream>>>(Mr_h, Mr_l, Wt_h, Wt_l,
                                                 b1, b2, ws12);
  k2_scores<<<(B_ * N_) / 4, 256, 0, stream>>>(ws12, mask, vw, ah, al);
  k3_mfma<<<dim3(2048 / 32, D_ / 32), 64, 0, stream>>>(ah, al, Mt_h, Mt_l, out);
}

// Round 9
// 75.615 us; speedup vs baseline: 1.2309x; 1.2309x over previous
//
#include <hip/hip_runtime.h>

#define B_ 4
#define N_ 512
#define D_ 768
#define A_ 128

typedef short bf16x8 __attribute__((ext_vector_type(8)));
typedef ushort u16x8 __attribute__((ext_vector_type(8)));
typedef float f32x4 __attribute__((ext_vector_type(4)));

__device__ __forceinline__ ushort f2h(float x) {  // f32 -> bf16 bits, RNE
  uint u = __builtin_bit_cast(uint, x);
  return (ushort)((u + 0x7fffu + ((u >> 16) & 1u)) >> 16);
}
__device__ __forceinline__ float h2f(ushort h) {
  uint u = ((uint)h) << 16;
  return __builtin_bit_cast(float, u);
}
__device__ __forceinline__ bf16x8 ld8(const ushort* p) {
  return *(const bf16x8*)p;
}
#define MFMA(a, b, c) __builtin_amdgcn_mfma_f32_16x16x32_bf16(a, b, c, 0, 0, 0)

// ---------------------------------------------------------------------------
// k0: fused prep (unchanged).
//  blocks 0..767: split M into bf16 hi/lo, Mr [2048][768] row-major (k1 A)
//                 and Mt [4][768][512] transposed (k3 B).
//  blocks 768..863: Wt[c][k] = (c<128?W1:W2)[k][c%128] bf16 hi/lo [256][768].
// ---------------------------------------------------------------------------
__global__ __launch_bounds__(256) void k0_prep(
    const float* __restrict__ M, const float* __restrict__ W1,
    const float* __restrict__ W2, ushort* __restrict__ Mr_h,
    ushort* __restrict__ Mr_l, ushort* __restrict__ Mt_h,
    ushort* __restrict__ Mt_l, ushort* __restrict__ Wt_h,
    ushort* __restrict__ Wt_l) {
  __shared__ ushort lds_h[64][40];
  __shared__ ushort lds_l[64][40];
  const int t = threadIdx.x;
  const int bid = blockIdx.x;
  if (bid < 768) {  // ---- M part ----
    const int dq = bid % 12;
    const int rest = bid / 12;
    const int d0 = dq * 64;
    const int n0 = (rest & 15) * 32;
    const int b = rest >> 4;
    const int n = t >> 3;          // 0..31
    const int dg = (t & 7) * 8;    // 0..56
    const size_t roff = ((size_t)(b * N_ + n0 + n)) * D_ + d0 + dg;
    const float4 v0 = *(const float4*)(M + roff);
    const float4 v1 = *(const float4*)(M + roff + 4);
    const float x[8] = {v0.x, v0.y, v0.z, v0.w, v1.x, v1.y, v1.z, v1.w};
    u16x8 vh, vl;
#pragma unroll
    for (int e = 0; e < 8; ++e) {
      ushort h = f2h(x[e]);
      ushort l = f2h(x[e] - h2f(h));
      vh[e] = h;
      vl[e] = l;
      lds_h[dg + e][n] = h;
      lds_l[dg + e][n] = l;
    }
    *(u16x8*)(Mr_h + roff) = vh;
    *(u16x8*)(Mr_l + roff) = vl;
    __syncthreads();
    const int dd = t >> 2;          // 0..63
    const int ng = (t & 3) * 8;     // 0..24
    const size_t toff = ((size_t)b * D_ + d0 + dd) * N_ + n0 + ng;
    *(u16x8*)(Mt_h + toff) = *(const u16x8*)(&lds_h[dd][ng]);
    *(u16x8*)(Mt_l + toff) = *(const u16x8*)(&lds_l[dd][ng]);
  } else {  // ---- W part ----
    const int c = t;
    const int k0 = (bid - 768) * 8;
    const float* __restrict__ Wp = (c < A_) ? W1 : W2;
    const int cc = c & (A_ - 1);
    u16x8 vh, vl;
#pragma unroll
    for (int e = 0; e < 8; ++e) {
      float x = Wp[(size_t)(k0 + e) * A_ + cc];
      ushort h = f2h(x);
      vh[e] = h;
      vl[e] = f2h(x - h2f(h));
    }
    *(u16x8*)(Wt_h + (size_t)c * D_ + k0) = vh;
    *(u16x8*)(Wt_l + (size_t)c * D_ + k0) = vl;
  }
}

// ---------------------------------------------------------------------------
// k1 v3: M @ [W1|W2] -> EXPONENTIALS.  MFMA 16x16x32 bf16, 3-pass split.
// K-SPLIT: block = 4 waves (256 thr), wave w computes K-range [192w,192w+192)
// of a 32x32 output tile; partials reduced via LDS. 512 blocks -> 8 waves/CU
// (vs 2 with 1-wave blocks). Epilogue: exp2((acc+bias)*SC):
//   cols 0..127  -> w1e[row][128]       (E1, row-major)
//   cols 128..255-> w2e[b][a][512]      (E2, transposed, coalesced col-runs)
// ---------------------------------------------------------------------------
__global__ __launch_bounds__(256) void k1_mfma(
    const ushort* __restrict__ Mr_h, const ushort* __restrict__ Mr_l,
    const ushort* __restrict__ Wt_h, const ushort* __restrict__ Wt_l,
    const float* __restrict__ b1, const float* __restrict__ b2,
    float* __restrict__ w1e, float* __restrict__ w2e) {
  __shared__ float l_red[4][32][33];  // 16.9 KB
  const int t = threadIdx.x;
  const int l = t & 63;
  const int w = t >> 6;
  const int r = l & 15, g = l >> 4;
  const int row0 = blockIdx.x * 32;
  const int cb = blockIdx.y * 32;
  const int kbase = w * 192;  // wave-private K-range (6 K-steps of 32)
  const size_t oA = (size_t)(row0 + r) * D_ + kbase + g * 8;
  const size_t oA2 = oA + (size_t)16 * D_;
  const size_t oB = (size_t)(cb + r) * D_ + kbase + g * 8;
  const size_t oB2 = oB + (size_t)16 * D_;
  f32x4 acc[2][2] = {};
  bf16x8 A[2][4], Bv[2][4];
#define K1LOAD(s, k0)                                                        \
  A[s][0] = ld8(Mr_h + oA + (k0));  A[s][1] = ld8(Mr_h + oA2 + (k0));        \
  A[s][2] = ld8(Mr_l + oA + (k0));  A[s][3] = ld8(Mr_l + oA2 + (k0));        \
  Bv[s][0] = ld8(Wt_h + oB + (k0)); Bv[s][1] = ld8(Wt_h + oB2 + (k0));       \
  Bv[s][2] = ld8(Wt_l + oB + (k0)); Bv[s][3] = ld8(Wt_l + oB2 + (k0));
#define K1MM(s)                                                              \
  acc[0][0] = MFMA(A[s][0], Bv[s][0], acc[0][0]);                            \
  acc[0][0] = MFMA(A[s][0], Bv[s][2], acc[0][0]);                            \
  acc[0][0] = MFMA(A[s][2], Bv[s][0], acc[0][0]);                            \
  acc[0][1] = MFMA(A[s][0], Bv[s][1], acc[0][1]);                            \
  acc[0][1] = MFMA(A[s][0], Bv[s][3], acc[0][1]);                            \
  acc[0][1] = MFMA(A[s][2], Bv[s][1], acc[0][1]);                            \
  acc[1][0] = MFMA(A[s][1], Bv[s][0], acc[1][0]);                            \
  acc[1][0] = MFMA(A[s][1], Bv[s][2], acc[1][0]);                            \
  acc[1][0] = MFMA(A[s][3], Bv[s][0], acc[1][0]);                            \
  acc[1][1] = MFMA(A[s][1], Bv[s][1], acc[1][1]);                            \
  acc[1][1] = MFMA(A[s][1], Bv[s][3], acc[1][1]);                            \
  acc[1][1] = MFMA(A[s][3], Bv[s][1], acc[1][1]);
  K1LOAD(0, 0)
#pragma unroll
  for (int kt = 0; kt < 6; ++kt) {
    if (kt & 1) {
      if (kt < 5) { K1LOAD(0, (kt + 1) * 32) }
      K1MM(1)
    } else {
      if (kt < 5) { K1LOAD(1, (kt + 1) * 32) }
      K1MM(0)
    }
  }
#undef K1LOAD
#undef K1MM
  // partials -> LDS
#pragma unroll
  for (int fi = 0; fi < 2; ++fi)
#pragma unroll
    for (int fj = 0; fj < 2; ++fj)
#pragma unroll
      for (int rr = 0; rr < 4; ++rr)
        l_red[w][fi * 16 + g * 4 + rr][fj * 16 + r] = acc[fi][fj][rr];
  __syncthreads();

  const float SC = 2.8853900817779268f;  // 2*log2(e): e^{2x} = 2^{SC*x}
  const int b = row0 >> 9;
  const int n0 = row0 & (N_ - 1);
  if (cb < A_) {  // E1: w1e[row][col], col-fast coalesced
#pragma unroll
    for (int k = 0; k < 4; ++k) {
      const int row = (t >> 5) + k * 8;
      const int col = t & 31;
      float v = l_red[0][row][col] + l_red[1][row][col] +
                l_red[2][row][col] + l_red[3][row][col];
      v = (v + b1[cb + col]) * SC;
      w1e[(size_t)(row0 + row) * A_ + cb + col] = __builtin_amdgcn_exp2f(v);
    }
  } else {  // E2: w2e[(b*128 + a)*512 + n], row(n)-fast coalesced
#pragma unroll
    for (int k = 0; k < 4; ++k) {
      const int row = t & 31;
      const int col = (t >> 5) + k * 8;
      float v = l_red[0][row][col] + l_red[1][row][col] +
                l_red[2][row][col] + l_red[3][row][col];
      v = (v + b2[cb - A_ + col]) * SC;
      w2e[(size_t)(b * A_ + cb - A_ + col) * N_ + n0 + row] =
          __builtin_amdgcn_exp2f(v);
    }
  }
}

// ---------------------------------------------------------------------------
// k2 v8: dense scores via FACTORED exponentials: e^{2(w1+w2)} = E1[i,a] *
// E2[a,j] (precomputed by k1) -> per element {mul, add, rcp, fma}: 1 trans
// + 3 VALU (was 2 trans + 5). Block = 4 waves = 4 rows; 8 j-tiles of 64.
// E2 tile double-buffered in LDS [128][64] (j-contig: staging coalesced,
// writes 2-way-free, reads bank=lane conflict-free). T14 async staging.
// Softmax identical to v7 (s[8] regs + butterfly).
// ---------------------------------------------------------------------------
__global__ __launch_bounds__(256) void k2_scores(
    const float* __restrict__ w1e, const float* __restrict__ w2e,
    const int* __restrict__ mask, const float* __restrict__ vw,
    ushort* __restrict__ ah, ushort* __restrict__ al) {
  __shared__ float l_w2[2][A_][64];  // 64 KB
  __shared__ float l_e1[4][A_];
  __shared__ float l_v2[A_];
  const int t = threadIdx.x;
  const int lane = t & 63;
  const int w = t >> 6;
  const int i0 = blockIdx.x * 4;
  const int b = i0 >> 9;
  const int i = i0 + w;

  for (int k = t; k < 4 * A_; k += 256)
    l_e1[k >> 7][k & 127] = w1e[(size_t)(i0 + (k >> 7)) * A_ + (k & 127)];
  if (t < A_) l_v2[t] = -2.f * vw[t];
  float vs = vw[lane] + vw[64 + lane];  // Vsum via butterfly
#pragma unroll
  for (int off = 32; off; off >>= 1) vs += __shfl_xor(vs, off);

  const float* __restrict__ w2src = w2e + (size_t)b * A_ * N_;
  float4 st[8];  // staging regs: tile = 128 a x 64 j = 2048 f4 / 256 thr

#define STAGE_LOAD(jt)                                                      \
  {                                                                         \
    const int j0 = (jt) * 64;                                               \
    _Pragma("unroll") for (int k = 0; k < 8; ++k) {                         \
      const int f = t + k * 256;                                            \
      const int a = f >> 4;                                                 \
      const int j4 = (f & 15) * 4;                                          \
      st[k] = *(const float4*)(w2src + (size_t)a * N_ + j0 + j4);           \
    }                                                                       \
  }
#define STAGE_WRITE(bf)                                                     \
  {                                                                         \
    _Pragma("unroll") for (int k = 0; k < 8; ++k) {                         \
      const int f = t + k * 256;                                            \
      const int a = f >> 4;                                                 \
      const int j4 = (f & 15) * 4;                                          \
      *(float4*)(&l_w2[bf][a][j4]) = st[k];                                 \
    }                                                                       \
  }

  STAGE_LOAD(0)
  STAGE_WRITE(0)
  __syncthreads();

  const float4* __restrict__ e1q = (const float4*)&l_e1[w][0];
  const float4* __restrict__ v2q = (const float4*)&l_v2[0];
  const float NEG = -3.402823466e38f;  // np.finfo(f32).min
  float s[8];
#pragma unroll
  for (int jt = 0; jt < 8; ++jt) {
    if (jt + 1 < 8) STAGE_LOAD(jt + 1)          // issue early (T14)
    const int mk = mask[(size_t)i * N_ + jt * 64 + lane];
    const float(*wb)[64] = l_w2[jt & 1];
    float acc = vs;
#pragma unroll 4
    for (int c = 0; c < 32; ++c) {
      const float4 wa = e1q[c];   // E1 broadcast (4 a's)
      const float4 vv = v2q[c];
      const float x0 = wb[c * 4 + 0][lane];  // E2, bank=lane
      const float x1 = wb[c * 4 + 1][lane];
      const float x2 = wb[c * 4 + 2][lane];
      const float x3 = wb[c * 4 + 3][lane];
      const float e0 = wa.x * x0;  // e^{2(w1+w2)} = E1*E2
      const float e1 = wa.y * x1;
      const float e2 = wa.z * x2;
      const float e3 = wa.w * x3;
      acc = fmaf(vv.x, __builtin_amdgcn_rcpf(e0 + 1.f), acc);
      acc = fmaf(vv.y, __builtin_amdgcn_rcpf(e1 + 1.f), acc);
      acc = fmaf(vv.z, __builtin_amdgcn_rcpf(e2 + 1.f), acc);
      acc = fmaf(vv.w, __builtin_amdgcn_rcpf(e3 + 1.f), acc);
    }
    s[jt] = mk ? acc : NEG;
    if (jt + 1 < 8) { STAGE_WRITE((jt + 1) & 1) }  // write late (T14)
    __syncthreads();
  }
#undef STAGE_LOAD
#undef STAGE_WRITE

  // fused softmax: 8 regs x 64 lanes = full row per wave
  float rmax = s[0];
#pragma unroll
  for (int jt = 1; jt < 8; ++jt) rmax = fmaxf(rmax, s[jt]);
#pragma unroll
  for (int off = 32; off; off >>= 1) rmax = fmaxf(rmax, __shfl_xor(rmax, off));
  const float L2E = 1.4426950408889634f;
  float psum = 0.f;
#pragma unroll
  for (int jt = 0; jt < 8; ++jt) {
    // all-masked row: s-rmax = 0 -> 1 -> uniform 1/512 (ref match);
    // masked in live row: (NEG-rmax)*L2E -> -inf -> exp2 = 0 exactly.
    s[jt] = __builtin_amdgcn_exp2f((s[jt] - rmax) * L2E);
    psum += s[jt];
  }
#pragma unroll
  for (int off = 32; off; off >>= 1) psum += __shfl_xor(psum, off);
  const float inv = __builtin_amdgcn_rcpf(psum);
#pragma unroll
  for (int jt = 0; jt < 8; ++jt) {
    const float pv = s[jt] * inv;
    const ushort hh = f2h(pv);
    ah[(size_t)i * N_ + jt * 64 + lane] = hh;
    al[(size_t)i * N_ + jt * 64 + lane] = f2h(pv - h2f(hh));
  }
}

// ---------------------------------------------------------------------------
// k3 v3: out[b] = attn[b] @ M[b].  MFMA 16x16x32 bf16, 3-pass split.
// K-SPLIT over j: block = 4 waves, wave w does j-range [128w,128w+128) of a
// 32x32 out tile; LDS reduce. 1536 blocks x 4 waves = 24 waves/CU.
// ---------------------------------------------------------------------------
__global__ __launch_bounds__(256) void k3_mfma(
    const ushort* __restrict__ ah, const ushort* __restrict__ al,
    const ushort* __restrict__ Mt_h, const ushort* __restrict__ Mt_l,
    float* __restrict__ out) {
  __shared__ float l_red[4][32][33];  // 16.9 KB
  const int t = threadIdx.x;
  const int l = t & 63;
  const int w = t >> 6;
  const int r = l & 15, g = l >> 4;
  const int row0 = blockIdx.x * 32;    // global row b*N+i
  const int d0 = blockIdx.y * 32;
  const int b = row0 >> 9;
  const int jbase = w * 128;  // wave-private j-range (4 K-steps of 32)
  const ushort* __restrict__ Bh = Mt_h + (size_t)b * D_ * N_;
  const ushort* __restrict__ Bl = Mt_l + (size_t)b * D_ * N_;
  const size_t oA = (size_t)(row0 + r) * N_ + jbase + g * 8;
  const size_t oA2 = oA + (size_t)16 * N_;
  const size_t oB = (size_t)(d0 + r) * N_ + jbase + g * 8;
  const size_t oB2 = oB + (size_t)16 * N_;
  f32x4 acc[2][2] = {};
  bf16x8 A[2][4], Bv[2][4];
#define K3LOAD(s, j0)                                                        \
  A[s][0] = ld8(ah + oA + (j0));  A[s][1] = ld8(ah + oA2 + (j0));            \
  A[s][2] = ld8(al + oA + (j0));  A[s][3] = ld8(al + oA2 + (j0));            \
  Bv[s][0] = ld8(Bh + oB + (j0)); Bv[s][1] = ld8(Bh + oB2 + (j0));           \
  Bv[s][2] = ld8(Bl + oB + (j0)); Bv[s][3] = ld8(Bl + oB2 + (j0));
#define K3MM(s)                                                              \
  acc[0][0] = MFMA(A[s][0], Bv[s][0], acc[0][0]);                            \
  acc[0][0] = MFMA(A[s][0], Bv[s][2], acc[0][0]);                            \
  acc[0][0] = MFMA(A[s][2], Bv[s][0], acc[0][0]);                            \
  acc[0][1] = MFMA(A[s][0], Bv[s][1], acc[0][1]);                            \
  acc[0][1] = MFMA(A[s][0], Bv[s][3], acc[0][1]);                            \
  acc[0][1] = MFMA(A[s][2], Bv[s][1], acc[0][1]);                            \
  acc[1][0] = MFMA(A[s][1], Bv[s][0], acc[1][0]);                            \
  acc[1][0] = MFMA(A[s][1], Bv[s][2], acc[1][0]);                            \
  acc[1][0] = MFMA(A[s][3], Bv[s][0], acc[1][0]);                            \
  acc[1][1] = MFMA(A[s][1], Bv[s][1], acc[1][1]);                            \
  acc[1][1] = MFMA(A[s][1], Bv[s][3], acc[1][1]);                            \
  acc[1][1] = MFMA(A[s][3], Bv[s][1], acc[1][1]);
  K3LOAD(0, 0)
#pragma unroll
  for (int kt = 0; kt < 4; ++kt) {
    if (kt & 1) {
      if (kt < 3) { K3LOAD(0, (kt + 1) * 32) }
      K3MM(1)
    } else {
      if (kt < 3) { K3LOAD(1, (kt + 1) * 32) }
      K3MM(0)
    }
  }
#undef K3LOAD
#undef K3MM
#pragma unroll
  for (int fi = 0; fi < 2; ++fi)
#pragma unroll
    for (int fd = 0; fd < 2; ++fd)
#pragma unroll
      for (int rr = 0; rr < 4; ++rr)
        l_red[w][fi * 16 + g * 4 + rr][fd * 16 + r] = acc[fi][fd][rr];
  __syncthreads();
#pragma unroll
  for (int k = 0; k < 4; ++k) {
    const int row = (t >> 5) + k * 8;
    const int col = t & 31;
    const float v = l_red[0][row][col] + l_red[1][row][col] +
                    l_red[2][row][col] + l_red[3][row][col];
    out[(size_t)(row0 + row) * D_ + d0 + col] = v;
  }
}

extern "C" void kernel_launch(void* const* d_in, const int* in_sizes, int n_in,
                              void* d_out, int out_size, void* d_ws,
                              size_t ws_size, hipStream_t stream) {
  const float* M = (const float*)d_in[0];
  const int* mask = (const int*)d_in[1];
  const float* W1 = (const float*)d_in[2];
  const float* b1 = (const float*)d_in[3];
  const float* W2 = (const float*)d_in[4];
  const float* b2 = (const float*)d_in[5];
  const float* vw = (const float*)d_in[6];
  float* out = (float*)d_out;

  // workspace carve-up: 18.75 MB total
  float* w1e = (float*)d_ws;                      // [2048][128] f32   1 MB
  float* w2e = w1e + 2048 * A_;                   // [4][128][512]     1 MB
  ushort* ah = (ushort*)(w2e + 4 * A_ * N_);      // [2048][512] bf16  2 MB
  ushort* al = ah + 2048 * N_;                    //                   2 MB
  ushort* Mr_h = al + 2048 * N_;                  // [2048][768] bf16  3 MB
  ushort* Mr_l = Mr_h + 2048 * D_;                //                   3 MB
  ushort* Mt_h = Mr_l + 2048 * D_;                // [4][768][512]     3 MB
  ushort* Mt_l = Mt_h + 2048 * D_;                //                   3 MB
  ushort* Wt_h = Mt_l + 2048 * D_;                // [256][768] bf16   .375
  ushort* Wt_l = Wt_h + 256 * D_;                 //                   .375

  k0_prep<<<864, 256, 0, stream>>>(M, W1, W2, Mr_h, Mr_l, Mt_h, Mt_l,
                                   Wt_h, Wt_l);
  k1_mfma<<<dim3(2048 / 32, 8), 256, 0, stream>>>(Mr_h, Mr_l, Wt_h, Wt_l,
                                                  b1, b2, w1e, w2e);
  k2_scores<<<(B_ * N_) / 4, 256, 0, stream>>>(w1e, w2e, mask, vw, ah, al);
  k3_mfma<<<dim3(2048 / 32, D_ / 32), 256, 0, stream>>>(ah, al, Mt_h, Mt_l,
                                                        out);
}

// Round 10
// 74.797 us; speedup vs baseline: 1.2444x; 1.0109x over previous
//
#include <hip/hip_runtime.h>

#define B_ 4
#define N_ 512
#define D_ 768
#define A_ 128

typedef short bf16x8 __attribute__((ext_vector_type(8)));
typedef ushort u16x8 __attribute__((ext_vector_type(8)));
typedef float f32x4 __attribute__((ext_vector_type(4)));

__device__ __forceinline__ ushort f2h(float x) {  // f32 -> bf16 bits, RNE
  uint u = __builtin_bit_cast(uint, x);
  return (ushort)((u + 0x7fffu + ((u >> 16) & 1u)) >> 16);
}
__device__ __forceinline__ float h2f(ushort h) {
  uint u = ((uint)h) << 16;
  return __builtin_bit_cast(float, u);
}
__device__ __forceinline__ bf16x8 ld8(const ushort* p) {
  return *(const bf16x8*)p;
}
#define MFMA(a, b, c) __builtin_amdgcn_mfma_f32_16x16x32_bf16(a, b, c, 0, 0, 0)

// ---------------------------------------------------------------------------
// k0: fused prep (unchanged).
//  blocks 0..767: split M into bf16 hi/lo, Mr [2048][768] row-major (k1 A)
//                 and Mt [4][768][512] transposed (k3 B).
//  blocks 768..863: Wt[c][k] = (c<128?W1:W2)[k][c%128] bf16 hi/lo [256][768].
// ---------------------------------------------------------------------------
__global__ __launch_bounds__(256) void k0_prep(
    const float* __restrict__ M, const float* __restrict__ W1,
    const float* __restrict__ W2, ushort* __restrict__ Mr_h,
    ushort* __restrict__ Mr_l, ushort* __restrict__ Mt_h,
    ushort* __restrict__ Mt_l, ushort* __restrict__ Wt_h,
    ushort* __restrict__ Wt_l) {
  __shared__ ushort lds_h[64][40];
  __shared__ ushort lds_l[64][40];
  const int t = threadIdx.x;
  const int bid = blockIdx.x;
  if (bid < 768) {  // ---- M part ----
    const int dq = bid % 12;
    const int rest = bid / 12;
    const int d0 = dq * 64;
    const int n0 = (rest & 15) * 32;
    const int b = rest >> 4;
    const int n = t >> 3;          // 0..31
    const int dg = (t & 7) * 8;    // 0..56
    const size_t roff = ((size_t)(b * N_ + n0 + n)) * D_ + d0 + dg;
    const float4 v0 = *(const float4*)(M + roff);
    const float4 v1 = *(const float4*)(M + roff + 4);
    const float x[8] = {v0.x, v0.y, v0.z, v0.w, v1.x, v1.y, v1.z, v1.w};
    u16x8 vh, vl;
#pragma unroll
    for (int e = 0; e < 8; ++e) {
      ushort h = f2h(x[e]);
      ushort l = f2h(x[e] - h2f(h));
      vh[e] = h;
      vl[e] = l;
      lds_h[dg + e][n] = h;
      lds_l[dg + e][n] = l;
    }
    *(u16x8*)(Mr_h + roff) = vh;
    *(u16x8*)(Mr_l + roff) = vl;
    __syncthreads();
    const int dd = t >> 2;          // 0..63
    const int ng = (t & 3) * 8;     // 0..24
    const size_t toff = ((size_t)b * D_ + d0 + dd) * N_ + n0 + ng;
    *(u16x8*)(Mt_h + toff) = *(const u16x8*)(&lds_h[dd][ng]);
    *(u16x8*)(Mt_l + toff) = *(const u16x8*)(&lds_l[dd][ng]);
  } else {  // ---- W part ----
    const int c = t;
    const int k0 = (bid - 768) * 8;
    const float* __restrict__ Wp = (c < A_) ? W1 : W2;
    const int cc = c & (A_ - 1);
    u16x8 vh, vl;
#pragma unroll
    for (int e = 0; e < 8; ++e) {
      float x = Wp[(size_t)(k0 + e) * A_ + cc];
      ushort h = f2h(x);
      vh[e] = h;
      vl[e] = f2h(x - h2f(h));
    }
    *(u16x8*)(Wt_h + (size_t)c * D_ + k0) = vh;
    *(u16x8*)(Wt_l + (size_t)c * D_ + k0) = vl;
  }
}

// ---------------------------------------------------------------------------
// k1 v3: M @ [W1|W2] -> EXPONENTIALS (unchanged).  MFMA 3-pass split,
// K-split 4-wave blocks, LDS reduce. Epilogue exp2((acc+bias)*SC):
//   cols 0..127  -> w1e[row][128]  (E1); cols 128..255 -> w2e[b][a][512] (E2).
// ---------------------------------------------------------------------------
__global__ __launch_bounds__(256) void k1_mfma(
    const ushort* __restrict__ Mr_h, const ushort* __restrict__ Mr_l,
    const ushort* __restrict__ Wt_h, const ushort* __restrict__ Wt_l,
    const float* __restrict__ b1, const float* __restrict__ b2,
    float* __restrict__ w1e, float* __restrict__ w2e) {
  __shared__ float l_red[4][32][33];  // 16.9 KB
  const int t = threadIdx.x;
  const int l = t & 63;
  const int w = t >> 6;
  const int r = l & 15, g = l >> 4;
  const int row0 = blockIdx.x * 32;
  const int cb = blockIdx.y * 32;
  const int kbase = w * 192;  // wave-private K-range (6 K-steps of 32)
  const size_t oA = (size_t)(row0 + r) * D_ + kbase + g * 8;
  const size_t oA2 = oA + (size_t)16 * D_;
  const size_t oB = (size_t)(cb + r) * D_ + kbase + g * 8;
  const size_t oB2 = oB + (size_t)16 * D_;
  f32x4 acc[2][2] = {};
  bf16x8 A[2][4], Bv[2][4];
#define K1LOAD(s, k0)                                                        \
  A[s][0] = ld8(Mr_h + oA + (k0));  A[s][1] = ld8(Mr_h + oA2 + (k0));        \
  A[s][2] = ld8(Mr_l + oA + (k0));  A[s][3] = ld8(Mr_l + oA2 + (k0));        \
  Bv[s][0] = ld8(Wt_h + oB + (k0)); Bv[s][1] = ld8(Wt_h + oB2 + (k0));       \
  Bv[s][2] = ld8(Wt_l + oB + (k0)); Bv[s][3] = ld8(Wt_l + oB2 + (k0));
#define K1MM(s)                                                              \
  acc[0][0] = MFMA(A[s][0], Bv[s][0], acc[0][0]);                            \
  acc[0][0] = MFMA(A[s][0], Bv[s][2], acc[0][0]);                            \
  acc[0][0] = MFMA(A[s][2], Bv[s][0], acc[0][0]);                            \
  acc[0][1] = MFMA(A[s][0], Bv[s][1], acc[0][1]);                            \
  acc[0][1] = MFMA(A[s][0], Bv[s][3], acc[0][1]);                            \
  acc[0][1] = MFMA(A[s][2], Bv[s][1], acc[0][1]);                            \
  acc[1][0] = MFMA(A[s][1], Bv[s][0], acc[1][0]);                            \
  acc[1][0] = MFMA(A[s][1], Bv[s][2], acc[1][0]);                            \
  acc[1][0] = MFMA(A[s][3], Bv[s][0], acc[1][0]);                            \
  acc[1][1] = MFMA(A[s][1], Bv[s][1], acc[1][1]);                            \
  acc[1][1] = MFMA(A[s][1], Bv[s][3], acc[1][1]);                            \
  acc[1][1] = MFMA(A[s][3], Bv[s][1], acc[1][1]);
  K1LOAD(0, 0)
#pragma unroll
  for (int kt = 0; kt < 6; ++kt) {
    if (kt & 1) {
      if (kt < 5) { K1LOAD(0, (kt + 1) * 32) }
      K1MM(1)
    } else {
      if (kt < 5) { K1LOAD(1, (kt + 1) * 32) }
      K1MM(0)
    }
  }
#undef K1LOAD
#undef K1MM
#pragma unroll
  for (int fi = 0; fi < 2; ++fi)
#pragma unroll
    for (int fj = 0; fj < 2; ++fj)
#pragma unroll
      for (int rr = 0; rr < 4; ++rr)
        l_red[w][fi * 16 + g * 4 + rr][fj * 16 + r] = acc[fi][fj][rr];
  __syncthreads();

  const float SC = 2.8853900817779268f;  // 2*log2(e): e^{2x} = 2^{SC*x}
  const int b = row0 >> 9;
  const int n0 = row0 & (N_ - 1);
  if (cb < A_) {  // E1: w1e[row][col], col-fast coalesced
#pragma unroll
    for (int k = 0; k < 4; ++k) {
      const int row = (t >> 5) + k * 8;
      const int col = t & 31;
      float v = l_red[0][row][col] + l_red[1][row][col] +
                l_red[2][row][col] + l_red[3][row][col];
      v = (v + b1[cb + col]) * SC;
      w1e[(size_t)(row0 + row) * A_ + cb + col] = __builtin_amdgcn_exp2f(v);
    }
  } else {  // E2: w2e[(b*128 + a)*512 + n], row(n)-fast coalesced
#pragma unroll
    for (int k = 0; k < 4; ++k) {
      const int row = t & 31;
      const int col = (t >> 5) + k * 8;
      float v = l_red[0][row][col] + l_red[1][row][col] +
                l_red[2][row][col] + l_red[3][row][col];
      v = (v + b2[cb - A_ + col]) * SC;
      w2e[(size_t)(b * A_ + cb - A_ + col) * N_ + n0 + row] =
          __builtin_amdgcn_exp2f(v);
    }
  }
}

// ---------------------------------------------------------------------------
// k2 v9: factored-exponential scores; 8 ROWS PER BLOCK (512 thr = 8 waves)
// to halve E2 L2 traffic (512MB -> 256MB: the hidden k2 cost), and fma-fold:
// G+1 = fmaf(E1,E2,1) -> per element {fma, rcp, fma} = 2 VALU + 1 trans.
// E2 tile [128 a][64 j] double-buffered in LDS (writes 2-way-free, reads
// bank=lane conflict-free), T14 async staging. LDS 68.5KB -> 2 blocks/CU
// -> 16 waves/CU. Softmax per wave: s[8] regs + butterfly (as v8).
// ---------------------------------------------------------------------------
__global__ __launch_bounds__(512) void k2_scores(
    const float* __restrict__ w1e, const float* __restrict__ w2e,
    const int* __restrict__ mask, const float* __restrict__ vw,
    ushort* __restrict__ ah, ushort* __restrict__ al) {
  __shared__ float l_w2[2][A_][64];  // 64 KB
  __shared__ float l_e1[8][A_];      // 4 KB
  __shared__ float l_v2[A_];
  const int t = threadIdx.x;
  const int lane = t & 63;
  const int w = t >> 6;
  const int i0 = blockIdx.x * 8;
  const int b = i0 >> 9;
  const int i = i0 + w;

  for (int k = t; k < 8 * A_; k += 512)
    l_e1[k >> 7][k & 127] = w1e[(size_t)(i0 + (k >> 7)) * A_ + (k & 127)];
  if (t < A_) l_v2[t] = -2.f * vw[t];
  float vs = vw[lane] + vw[64 + lane];  // Vsum via butterfly
#pragma unroll
  for (int off = 32; off; off >>= 1) vs += __shfl_xor(vs, off);

  const float* __restrict__ w2src = w2e + (size_t)b * A_ * N_;
  float4 st[4];  // staging regs: tile = 128 a x 64 j = 2048 f4 / 512 thr

#define STAGE_LOAD(jt)                                                      \
  {                                                                         \
    const int j0 = (jt) * 64;                                               \
    _Pragma("unroll") for (int k = 0; k < 4; ++k) {                         \
      const int f = t + k * 512;                                            \
      const int a = f >> 4;                                                 \
      const int j4 = (f & 15) * 4;                                          \
      st[k] = *(const float4*)(w2src + (size_t)a * N_ + j0 + j4);           \
    }                                                                       \
  }
#define STAGE_WRITE(bf)                                                     \
  {                                                                         \
    _Pragma("unroll") for (int k = 0; k < 4; ++k) {                         \
      const int f = t + k * 512;                                            \
      const int a = f >> 4;                                                 \
      const int j4 = (f & 15) * 4;                                          \
      *(float4*)(&l_w2[bf][a][j4]) = st[k];                                 \
    }                                                                       \
  }

  STAGE_LOAD(0)
  STAGE_WRITE(0)
  __syncthreads();

  const float4* __restrict__ e1q = (const float4*)&l_e1[w][0];
  const float4* __restrict__ v2q = (const float4*)&l_v2[0];
  const float NEG = -3.402823466e38f;  // np.finfo(f32).min
  float s[8];
#pragma unroll
  for (int jt = 0; jt < 8; ++jt) {
    if (jt + 1 < 8) STAGE_LOAD(jt + 1)          // issue early (T14)
    const int mk = mask[(size_t)i * N_ + jt * 64 + lane];
    const float(*wb)[64] = l_w2[jt & 1];
    float acc = vs;
#pragma unroll 4
    for (int c = 0; c < 32; ++c) {
      const float4 wa = e1q[c];   // E1 broadcast (4 a's)
      const float4 vv = v2q[c];
      const float x0 = wb[c * 4 + 0][lane];  // E2, bank=lane
      const float x1 = wb[c * 4 + 1][lane];
      const float x2 = wb[c * 4 + 2][lane];
      const float x3 = wb[c * 4 + 3][lane];
      const float g0 = fmaf(wa.x, x0, 1.f);  // E1*E2 + 1 in one fma
      const float g1 = fmaf(wa.y, x1, 1.f);
      const float g2 = fmaf(wa.z, x2, 1.f);
      const float g3 = fmaf(wa.w, x3, 1.f);
      acc = fmaf(vv.x, __builtin_amdgcn_rcpf(g0), acc);
      acc = fmaf(vv.y, __builtin_amdgcn_rcpf(g1), acc);
      acc = fmaf(vv.z, __builtin_amdgcn_rcpf(g2), acc);
      acc = fmaf(vv.w, __builtin_amdgcn_rcpf(g3), acc);
    }
    s[jt] = mk ? acc : NEG;
    if (jt + 1 < 8) { STAGE_WRITE((jt + 1) & 1) }  // write late (T14)
    __syncthreads();
  }
#undef STAGE_LOAD
#undef STAGE_WRITE

  // fused softmax: 8 regs x 64 lanes = full row per wave
  float rmax = s[0];
#pragma unroll
  for (int jt = 1; jt < 8; ++jt) rmax = fmaxf(rmax, s[jt]);
#pragma unroll
  for (int off = 32; off; off >>= 1) rmax = fmaxf(rmax, __shfl_xor(rmax, off));
  const float L2E = 1.4426950408889634f;
  float psum = 0.f;
#pragma unroll
  for (int jt = 0; jt < 8; ++jt) {
    // all-masked row: s-rmax = 0 -> 1 -> uniform 1/512 (ref match);
    // masked in live row: (NEG-rmax)*L2E -> -inf -> exp2 = 0 exactly.
    s[jt] = __builtin_amdgcn_exp2f((s[jt] - rmax) * L2E);
    psum += s[jt];
  }
#pragma unroll
  for (int off = 32; off; off >>= 1) psum += __shfl_xor(psum, off);
  const float inv = __builtin_amdgcn_rcpf(psum);
#pragma unroll
  for (int jt = 0; jt < 8; ++jt) {
    const float pv = s[jt] * inv;
    const ushort hh = f2h(pv);
    ah[(size_t)i * N_ + jt * 64 + lane] = hh;
    al[(size_t)i * N_ + jt * 64 + lane] = f2h(pv - h2f(hh));
  }
}

// ---------------------------------------------------------------------------
// k3 v3: out[b] = attn[b] @ M[b] (unchanged).  MFMA 3-pass split, K-split
// over j: 4-wave blocks, LDS reduce. 1536 blocks x 4 waves = 24 waves/CU.
// ---------------------------------------------------------------------------
__global__ __launch_bounds__(256) void k3_mfma(
    const ushort* __restrict__ ah, const ushort* __restrict__ al,
    const ushort* __restrict__ Mt_h, const ushort* __restrict__ Mt_l,
    float* __restrict__ out) {
  __shared__ float l_red[4][32][33];  // 16.9 KB
  const int t = threadIdx.x;
  const int l = t & 63;
  const int w = t >> 6;
  const int r = l & 15, g = l >> 4;
  const int row0 = blockIdx.x * 32;    // global row b*N+i
  const int d0 = blockIdx.y * 32;
  const int b = row0 >> 9;
  const int jbase = w * 128;  // wave-private j-range (4 K-steps of 32)
  const ushort* __restrict__ Bh = Mt_h + (size_t)b * D_ * N_;
  const ushort* __restrict__ Bl = Mt_l + (size_t)b * D_ * N_;
  const size_t oA = (size_t)(row0 + r) * N_ + jbase + g * 8;
  const size_t oA2 = oA + (size_t)16 * N_;
  const size_t oB = (size_t)(d0 + r) * N_ + jbase + g * 8;
  const size_t oB2 = oB + (size_t)16 * N_;
  f32x4 acc[2][2] = {};
  bf16x8 A[2][4], Bv[2][4];
#define K3LOAD(s, j0)                                                        \
  A[s][0] = ld8(ah + oA + (j0));  A[s][1] = ld8(ah + oA2 + (j0));            \
  A[s][2] = ld8(al + oA + (j0));  A[s][3] = ld8(al + oA2 + (j0));            \
  Bv[s][0] = ld8(Bh + oB + (j0)); Bv[s][1] = ld8(Bh + oB2 + (j0));           \
  Bv[s][2] = ld8(Bl + oB + (j0)); Bv[s][3] = ld8(Bl + oB2 + (j0));
#define K3MM(s)                                                              \
  acc[0][0] = MFMA(A[s][0], Bv[s][0], acc[0][0]);                            \
  acc[0][0] = MFMA(A[s][0], Bv[s][2], acc[0][0]);                            \
  acc[0][0] = MFMA(A[s][2], Bv[s][0], acc[0][0]);                            \
  acc[0][1] = MFMA(A[s][0], Bv[s][1], acc[0][1]);                            \
  acc[0][1] = MFMA(A[s][0], Bv[s][3], acc[0][1]);                            \
  acc[0][1] = MFMA(A[s][2], Bv[s][1], acc[0][1]);                            \
  acc[1][0] = MFMA(A[s][1], Bv[s][0], acc[1][0]);                            \
  acc[1][0] = MFMA(A[s][1], Bv[s][2], acc[1][0]);                            \
  acc[1][0] = MFMA(A[s][3], Bv[s][0], acc[1][0]);                            \
  acc[1][1] = MFMA(A[s][1], Bv[s][1], acc[1][1]);                            \
  acc[1][1] = MFMA(A[s][1], Bv[s][3], acc[1][1]);                            \
  acc[1][1] = MFMA(A[s][3], Bv[s][1], acc[1][1]);
  K3LOAD(0, 0)
#pragma unroll
  for (int kt = 0; kt < 4; ++kt) {
    if (kt & 1) {
      if (kt < 3) { K3LOAD(0, (kt + 1) * 32) }
      K3MM(1)
    } else {
      if (kt < 3) { K3LOAD(1, (kt + 1) * 32) }
      K3MM(0)
    }
  }
#undef K3LOAD
#undef K3MM
#pragma unroll
  for (int fi = 0; fi < 2; ++fi)
#pragma unroll
    for (int fd = 0; fd < 2; ++fd)
#pragma unroll
      for (int rr = 0; rr < 4; ++rr)
        l_red[w][fi * 16 + g * 4 + rr][fd * 16 + r] = acc[fi][fd][rr];
  __syncthreads();
#pragma unroll
  for (int k = 0; k < 4; ++k) {
    const int row = (t >> 5) + k * 8;
    const int col = t & 31;
    const float v = l_red[0][row][col] + l_red[1][row][col] +
                    l_red[2][row][col] + l_red[3][row][col];
    out[(size_t)(row0 + row) * D_ + d0 + col] = v;
  }
}

extern "C" void kernel_launch(void* const* d_in, const int* in_sizes, int n_in,
                              void* d_out, int out_size, void* d_ws,
                              size_t ws_size, hipStream_t stream) {
  const float* M = (const float*)d_in[0];
  const int* mask = (const int*)d_in[1];
  const float* W1 = (const float*)d_in[2];
  const float* b1 = (const float*)d_in[3];
  const float* W2 = (const float*)d_in[4];
  const float* b2 = (const float*)d_in[5];
  const float* vw = (const float*)d_in[6];
  float* out = (float*)d_out;

  // workspace carve-up: 18.75 MB total
  float* w1e = (float*)d_ws;                      // [2048][128] f32   1 MB
  float* w2e = w1e + 2048 * A_;                   // [4][128][512]     1 MB
  ushort* ah = (ushort*)(w2e + 4 * A_ * N_);      // [2048][512] bf16  2 MB
  ushort* al = ah + 2048 * N_;                    //                   2 MB
  ushort* Mr_h = al + 2048 * N_;                  // [2048][768] bf16  3 MB
  ushort* Mr_l = Mr_h + 2048 * D_;                //                   3 MB
  ushort* Mt_h = Mr_l + 2048 * D_;                // [4][768][512]     3 MB
  ushort* Mt_l = Mt_h + 2048 * D_;                //                   3 MB
  ushort* Wt_h = Mt_l + 2048 * D_;                // [256][768] bf16   .375
  ushort* Wt_l = Wt_h + 256 * D_;                 //                   .375

  k0_prep<<<864, 256, 0, stream>>>(M, W1, W2, Mr_h, Mr_l, Mt_h, Mt_l,
                                   Wt_h, Wt_l);
  k1_mfma<<<dim3(2048 / 32, 8), 256, 0, stream>>>(Mr_h, Mr_l, Wt_h, Wt_l,
                                                  b1, b2, w1e, w2e);
  k2_scores<<<(B_ * N_) / 8, 512, 0, stream>>>(w1e, w2e, mask, vw, ah, al);
  k3_mfma<<<dim3(2048 / 32, D_ / 32), 256, 0, stream>>>(ah, al, Mt_h, Mt_l,
                                                        out);
}

// Round 11
// 69.287 us; speedup vs baseline: 1.3434x; 1.0795x over previous
//
#include <hip/hip_runtime.h>

#define B_ 4
#define N_ 512
#define D_ 768
#define A_ 128

typedef short bf16x8 __attribute__((ext_vector_type(8)));
typedef ushort u16x8 __attribute__((ext_vector_type(8)));
typedef float f32x4 __attribute__((ext_vector_type(4)));

__device__ __forceinline__ ushort f2h(float x) {  // f32 -> bf16 bits, RNE
  uint u = __builtin_bit_cast(uint, x);
  return (ushort)((u + 0x7fffu + ((u >> 16) & 1u)) >> 16);
}
__device__ __forceinline__ float h2f(ushort h) {
  uint u = ((uint)h) << 16;
  return __builtin_bit_cast(float, u);
}
__device__ __forceinline__ bf16x8 ld8(const ushort* p) {
  return *(const bf16x8*)p;
}
#define MFMA(a, b, c) __builtin_amdgcn_mfma_f32_16x16x32_bf16(a, b, c, 0, 0, 0)

// ---------------------------------------------------------------------------
// k0: fused prep (unchanged).
// ---------------------------------------------------------------------------
__global__ __launch_bounds__(256) void k0_prep(
    const float* __restrict__ M, const float* __restrict__ W1,
    const float* __restrict__ W2, ushort* __restrict__ Mr_h,
    ushort* __restrict__ Mr_l, ushort* __restrict__ Mt_h,
    ushort* __restrict__ Mt_l, ushort* __restrict__ Wt_h,
    ushort* __restrict__ Wt_l) {
  __shared__ ushort lds_h[64][40];
  __shared__ ushort lds_l[64][40];
  const int t = threadIdx.x;
  const int bid = blockIdx.x;
  if (bid < 768) {  // ---- M part ----
    const int dq = bid % 12;
    const int rest = bid / 12;
    const int d0 = dq * 64;
    const int n0 = (rest & 15) * 32;
    const int b = rest >> 4;
    const int n = t >> 3;          // 0..31
    const int dg = (t & 7) * 8;    // 0..56
    const size_t roff = ((size_t)(b * N_ + n0 + n)) * D_ + d0 + dg;
    const float4 v0 = *(const float4*)(M + roff);
    const float4 v1 = *(const float4*)(M + roff + 4);
    const float x[8] = {v0.x, v0.y, v0.z, v0.w, v1.x, v1.y, v1.z, v1.w};
    u16x8 vh, vl;
#pragma unroll
    for (int e = 0; e < 8; ++e) {
      ushort h = f2h(x[e]);
      ushort l = f2h(x[e] - h2f(h));
      vh[e] = h;
      vl[e] = l;
      lds_h[dg + e][n] = h;
      lds_l[dg + e][n] = l;
    }
    *(u16x8*)(Mr_h + roff) = vh;
    *(u16x8*)(Mr_l + roff) = vl;
    __syncthreads();
    const int dd = t >> 2;          // 0..63
    const int ng = (t & 3) * 8;     // 0..24
    const size_t toff = ((size_t)b * D_ + d0 + dd) * N_ + n0 + ng;
    *(u16x8*)(Mt_h + toff) = *(const u16x8*)(&lds_h[dd][ng]);
    *(u16x8*)(Mt_l + toff) = *(const u16x8*)(&lds_l[dd][ng]);
  } else {  // ---- W part ----
    const int c = t;
    const int k0 = (bid - 768) * 8;
    const float* __restrict__ Wp = (c < A_) ? W1 : W2;
    const int cc = c & (A_ - 1);
    u16x8 vh, vl;
#pragma unroll
    for (int e = 0; e < 8; ++e) {
      float x = Wp[(size_t)(k0 + e) * A_ + cc];
      ushort h = f2h(x);
      vh[e] = h;
      vl[e] = f2h(x - h2f(h));
    }
    *(u16x8*)(Wt_h + (size_t)c * D_ + k0) = vh;
    *(u16x8*)(Wt_l + (size_t)c * D_ + k0) = vl;
  }
}

// ---------------------------------------------------------------------------
// k1 v3: M @ [W1|W2] -> EXPONENTIALS (unchanged).
// ---------------------------------------------------------------------------
__global__ __launch_bounds__(256) void k1_mfma(
    const ushort* __restrict__ Mr_h, const ushort* __restrict__ Mr_l,
    const ushort* __restrict__ Wt_h, const ushort* __restrict__ Wt_l,
    const float* __restrict__ b1, const float* __restrict__ b2,
    float* __restrict__ w1e, float* __restrict__ w2e) {
  __shared__ float l_red[4][32][33];  // 16.9 KB
  const int t = threadIdx.x;
  const int l = t & 63;
  const int w = t >> 6;
  const int r = l & 15, g = l >> 4;
  const int row0 = blockIdx.x * 32;
  const int cb = blockIdx.y * 32;
  const int kbase = w * 192;  // wave-private K-range (6 K-steps of 32)
  const size_t oA = (size_t)(row0 + r) * D_ + kbase + g * 8;
  const size_t oA2 = oA + (size_t)16 * D_;
  const size_t oB = (size_t)(cb + r) * D_ + kbase + g * 8;
  const size_t oB2 = oB + (size_t)16 * D_;
  f32x4 acc[2][2] = {};
  bf16x8 A[2][4], Bv[2][4];
#define K1LOAD(s, k0)                                                        \
  A[s][0] = ld8(Mr_h + oA + (k0));  A[s][1] = ld8(Mr_h + oA2 + (k0));        \
  A[s][2] = ld8(Mr_l + oA + (k0));  A[s][3] = ld8(Mr_l + oA2 + (k0));        \
  Bv[s][0] = ld8(Wt_h + oB + (k0)); Bv[s][1] = ld8(Wt_h + oB2 + (k0));       \
  Bv[s][2] = ld8(Wt_l + oB + (k0)); Bv[s][3] = ld8(Wt_l + oB2 + (k0));
#define K1MM(s)                                                              \
  acc[0][0] = MFMA(A[s][0], Bv[s][0], acc[0][0]);                            \
  acc[0][0] = MFMA(A[s][0], Bv[s][2], acc[0][0]);                            \
  acc[0][0] = MFMA(A[s][2], Bv[s][0], acc[0][0]);                            \
  acc[0][1] = MFMA(A[s][0], Bv[s][1], acc[0][1]);                            \
  acc[0][1] = MFMA(A[s][0], Bv[s][3], acc[0][1]);                            \
  acc[0][1] = MFMA(A[s][2], Bv[s][1], acc[0][1]);                            \
  acc[1][0] = MFMA(A[s][1], Bv[s][0], acc[1][0]);                            \
  acc[1][0] = MFMA(A[s][1], Bv[s][2], acc[1][0]);                            \
  acc[1][0] = MFMA(A[s][3], Bv[s][0], acc[1][0]);                            \
  acc[1][1] = MFMA(A[s][1], Bv[s][1], acc[1][1]);                            \
  acc[1][1] = MFMA(A[s][1], Bv[s][3], acc[1][1]);                            \
  acc[1][1] = MFMA(A[s][3], Bv[s][1], acc[1][1]);
  K1LOAD(0, 0)
#pragma unroll
  for (int kt = 0; kt < 6; ++kt) {
    if (kt & 1) {
      if (kt < 5) { K1LOAD(0, (kt + 1) * 32) }
      K1MM(1)
    } else {
      if (kt < 5) { K1LOAD(1, (kt + 1) * 32) }
      K1MM(0)
    }
  }
#undef K1LOAD
#undef K1MM
#pragma unroll
  for (int fi = 0; fi < 2; ++fi)
#pragma unroll
    for (int fj = 0; fj < 2; ++fj)
#pragma unroll
      for (int rr = 0; rr < 4; ++rr)
        l_red[w][fi * 16 + g * 4 + rr][fj * 16 + r] = acc[fi][fj][rr];
  __syncthreads();

  const float SC = 2.8853900817779268f;  // 2*log2(e): e^{2x} = 2^{SC*x}
  const int b = row0 >> 9;
  const int n0 = row0 & (N_ - 1);
  if (cb < A_) {  // E1: w1e[row][col], col-fast coalesced
#pragma unroll
    for (int k = 0; k < 4; ++k) {
      const int row = (t >> 5) + k * 8;
      const int col = t & 31;
      float v = l_red[0][row][col] + l_red[1][row][col] +
                l_red[2][row][col] + l_red[3][row][col];
      v = (v + b1[cb + col]) * SC;
      w1e[(size_t)(row0 + row) * A_ + cb + col] = __builtin_amdgcn_exp2f(v);
    }
  } else {  // E2: w2e[(b*128 + a)*512 + n], row(n)-fast coalesced
#pragma unroll
    for (int k = 0; k < 4; ++k) {
      const int row = t & 31;
      const int col = (t >> 5) + k * 8;
      float v = l_red[0][row][col] + l_red[1][row][col] +
                l_red[2][row][col] + l_red[3][row][col];
      v = (v + b2[cb - A_ + col]) * SC;
      w2e[(size_t)(b * A_ + cb - A_ + col) * N_ + n0 + row] =
          __builtin_amdgcn_exp2f(v);
    }
  }
}

// ---------------------------------------------------------------------------
// k2 v10: E1/v broadcasts moved OFF the LDS pipe into SGPRs.
// E1[i,a] and v[a] are wave-uniform -> readfirstlane(i) forces the row
// pointer scalar -> clang emits s_load_dwordx4 (SMEM/K$ path). LDS now
// holds ONLY the E2 tile (4 ds_read_b32/c/wave = 8 clk, was 24).
// Math: acc2 = sum_a v[a]*rcp(fma(E1,E2,1)); s = vs - 2*acc2.
// 8 rows/block (512 thr), double-buffered tile, T14 staging as v9.
// ---------------------------------------------------------------------------
__global__ __launch_bounds__(512) void k2_scores(
    const float* __restrict__ w1e, const float* __restrict__ w2e,
    const int* __restrict__ mask, const float* __restrict__ vw,
    ushort* __restrict__ ah, ushort* __restrict__ al) {
  __shared__ float l_w2[2][A_][64];  // 64 KB
  const int t = threadIdx.x;
  const int lane = t & 63;
  const int w = t >> 6;
  const int i0 = blockIdx.x * 8;
  const int b = i0 >> 9;
  const int i = i0 + w;
  // wave-uniform row pointer -> scalar loads for E1
  const int iu = __builtin_amdgcn_readfirstlane(i);
  const float* __restrict__ w1row = w1e + (size_t)iu * A_;

  float vs = vw[lane] + vw[64 + lane];  // Vsum via butterfly
#pragma unroll
  for (int off = 32; off; off >>= 1) vs += __shfl_xor(vs, off);

  const float* __restrict__ w2src = w2e + (size_t)b * A_ * N_;
  float4 st[4];  // staging regs: tile = 128 a x 64 j = 2048 f4 / 512 thr

#define STAGE_LOAD(jt)                                                      \
  {                                                                         \
    const int j0 = (jt) * 64;                                               \
    _Pragma("unroll") for (int k = 0; k < 4; ++k) {                         \
      const int f = t + k * 512;                                            \
      const int a = f >> 4;                                                 \
      const int j4 = (f & 15) * 4;                                          \
      st[k] = *(const float4*)(w2src + (size_t)a * N_ + j0 + j4);           \
    }                                                                       \
  }
#define STAGE_WRITE(bf)                                                     \
  {                                                                         \
    _Pragma("unroll") for (int k = 0; k < 4; ++k) {                         \
      const int f = t + k * 512;                                            \
      const int a = f >> 4;                                                 \
      const int j4 = (f & 15) * 4;                                          \
      *(float4*)(&l_w2[bf][a][j4]) = st[k];                                 \
    }                                                                       \
  }

  STAGE_LOAD(0)
  STAGE_WRITE(0)
  __syncthreads();

  const float NEG = -3.402823466e38f;  // np.finfo(f32).min
  float s[8];
#pragma unroll
  for (int jt = 0; jt < 8; ++jt) {
    if (jt + 1 < 8) STAGE_LOAD(jt + 1)          // issue early (T14)
    const int mk = mask[(size_t)i * N_ + jt * 64 + lane];
    const float(*wb)[64] = l_w2[jt & 1];
    float acc2 = 0.f;
#pragma unroll 4
    for (int c = 0; c < 32; ++c) {
      const float4 wa = *(const float4*)(w1row + c * 4);  // s_load (SGPR)
      const float4 vv = *(const float4*)(vw + c * 4);     // s_load (SGPR)
      const float x0 = wb[c * 4 + 0][lane];  // E2, bank=lane (free)
      const float x1 = wb[c * 4 + 1][lane];
      const float x2 = wb[c * 4 + 2][lane];
      const float x3 = wb[c * 4 + 3][lane];
      const float g0 = fmaf(wa.x, x0, 1.f);  // 1 SGPR operand per VALU op
      const float g1 = fmaf(wa.y, x1, 1.f);
      const float g2 = fmaf(wa.z, x2, 1.f);
      const float g3 = fmaf(wa.w, x3, 1.f);
      acc2 = fmaf(vv.x, __builtin_amdgcn_rcpf(g0), acc2);
      acc2 = fmaf(vv.y, __builtin_amdgcn_rcpf(g1), acc2);
      acc2 = fmaf(vv.z, __builtin_amdgcn_rcpf(g2), acc2);
      acc2 = fmaf(vv.w, __builtin_amdgcn_rcpf(g3), acc2);
    }
    s[jt] = mk ? fmaf(-2.f, acc2, vs) : NEG;
    if (jt + 1 < 8) { STAGE_WRITE((jt + 1) & 1) }  // write late (T14)
    __syncthreads();
  }
#undef STAGE_LOAD
#undef STAGE_WRITE

  // fused softmax: 8 regs x 64 lanes = full row per wave
  float rmax = s[0];
#pragma unroll
  for (int jt = 1; jt < 8; ++jt) rmax = fmaxf(rmax, s[jt]);
#pragma unroll
  for (int off = 32; off; off >>= 1) rmax = fmaxf(rmax, __shfl_xor(rmax, off));
  const float L2E = 1.4426950408889634f;
  float psum = 0.f;
#pragma unroll
  for (int jt = 0; jt < 8; ++jt) {
    // all-masked row: s-rmax = 0 -> 1 -> uniform 1/512 (ref match);
    // masked in live row: (NEG-rmax)*L2E -> -inf -> exp2 = 0 exactly.
    s[jt] = __builtin_amdgcn_exp2f((s[jt] - rmax) * L2E);
    psum += s[jt];
  }
#pragma unroll
  for (int off = 32; off; off >>= 1) psum += __shfl_xor(psum, off);
  const float inv = __builtin_amdgcn_rcpf(psum);
#pragma unroll
  for (int jt = 0; jt < 8; ++jt) {
    const float pv = s[jt] * inv;
    const ushort hh = f2h(pv);
    ah[(size_t)i * N_ + jt * 64 + lane] = hh;
    al[(size_t)i * N_ + jt * 64 + lane] = f2h(pv - h2f(hh));
  }
}

// ---------------------------------------------------------------------------
// k3 v4: out[b] = attn[b] @ M[b].  64 rows x 32 d tiles (L2 traffic 201 ->
// 151 MB), MFMA 3-pass split, K-split over j: 4 waves x 128 j, LDS reduce.
// Grid 768 blocks x 4 waves = 12 waves/CU.
// ---------------------------------------------------------------------------
__global__ __launch_bounds__(256) void k3_mfma(
    const ushort* __restrict__ ah, const ushort* __restrict__ al,
    const ushort* __restrict__ Mt_h, const ushort* __restrict__ Mt_l,
    float* __restrict__ out) {
  __shared__ float l_red[4][64][33];  // 33.8 KB
  const int t = threadIdx.x;
  const int l = t & 63;
  const int w = t >> 6;
  const int r = l & 15, g = l >> 4;
  const int row0 = blockIdx.x * 64;    // global row b*N+i (64 | 512)
  const int d0 = blockIdx.y * 32;
  const int b = row0 >> 9;
  const int jbase = w * 128;  // wave-private j-range (4 K-steps of 32)
  const ushort* __restrict__ Bh = Mt_h + (size_t)b * D_ * N_;
  const ushort* __restrict__ Bl = Mt_l + (size_t)b * D_ * N_;
  size_t oA[4];
#pragma unroll
  for (int fi = 0; fi < 4; ++fi)
    oA[fi] = (size_t)(row0 + fi * 16 + r) * N_ + jbase + g * 8;
  const size_t oB = (size_t)(d0 + r) * N_ + jbase + g * 8;
  const size_t oB2 = oB + (size_t)16 * N_;
  f32x4 acc[4][2] = {};
  bf16x8 A[2][8], Bv[2][4];
#define K3LOAD(s, j0)                                                        \
  A[s][0] = ld8(ah + oA[0] + (j0)); A[s][1] = ld8(ah + oA[1] + (j0));        \
  A[s][2] = ld8(ah + oA[2] + (j0)); A[s][3] = ld8(ah + oA[3] + (j0));        \
  A[s][4] = ld8(al + oA[0] + (j0)); A[s][5] = ld8(al + oA[1] + (j0));        \
  A[s][6] = ld8(al + oA[2] + (j0)); A[s][7] = ld8(al + oA[3] + (j0));        \
  Bv[s][0] = ld8(Bh + oB + (j0));   Bv[s][1] = ld8(Bh + oB2 + (j0));         \
  Bv[s][2] = ld8(Bl + oB + (j0));   Bv[s][3] = ld8(Bl + oB2 + (j0));
#define K3MM(s)                                                              \
  _Pragma("unroll") for (int fi = 0; fi < 4; ++fi)                           \
  _Pragma("unroll") for (int fd = 0; fd < 2; ++fd) {                         \
    acc[fi][fd] = MFMA(A[s][fi], Bv[s][fd], acc[fi][fd]);                    \
    acc[fi][fd] = MFMA(A[s][fi], Bv[s][fd + 2], acc[fi][fd]);                \
    acc[fi][fd] = MFMA(A[s][fi + 4], Bv[s][fd], acc[fi][fd]);                \
  }
  K3LOAD(0, 0)
#pragma unroll
  for (int kt = 0; kt < 4; ++kt) {
    if (kt & 1) {
      if (kt < 3) { K3LOAD(0, (kt + 1) * 32) }
      K3MM(1)
    } else {
      if (kt < 3) { K3LOAD(1, (kt + 1) * 32) }
      K3MM(0)
    }
  }
#undef K3LOAD
#undef K3MM
#pragma unroll
  for (int fi = 0; fi < 4; ++fi)
#pragma unroll
    for (int fd = 0; fd < 2; ++fd)
#pragma unroll
      for (int rr = 0; rr < 4; ++rr)
        l_red[w][fi * 16 + g * 4 + rr][fd * 16 + r] = acc[fi][fd][rr];
  __syncthreads();
#pragma unroll
  for (int k = 0; k < 8; ++k) {
    const int row = (t >> 5) + k * 8;
    const int col = t & 31;
    const float v = l_red[0][row][col] + l_red[1][row][col] +
                    l_red[2][row][col] + l_red[3][row][col];
    out[(size_t)(row0 + row) * D_ + d0 + col] = v;
  }
}

extern "C" void kernel_launch(void* const* d_in, const int* in_sizes, int n_in,
                              void* d_out, int out_size, void* d_ws,
                              size_t ws_size, hipStream_t stream) {
  const float* M = (const float*)d_in[0];
  const int* mask = (const int*)d_in[1];
  const float* W1 = (const float*)d_in[2];
  const float* b1 = (const float*)d_in[3];
  const float* W2 = (const float*)d_in[4];
  const float* b2 = (const float*)d_in[5];
  const float* vw = (const float*)d_in[6];
  float* out = (float*)d_out;

  // workspace carve-up: 18.75 MB total
  float* w1e = (float*)d_ws;                      // [2048][128] f32   1 MB
  float* w2e = w1e + 2048 * A_;                   // [4][128][512]     1 MB
  ushort* ah = (ushort*)(w2e + 4 * A_ * N_);      // [2048][512] bf16  2 MB
  ushort* al = ah + 2048 * N_;                    //                   2 MB
  ushort* Mr_h = al + 2048 * N_;                  // [2048][768] bf16  3 MB
  ushort* Mr_l = Mr_h + 2048 * D_;                //                   3 MB
  ushort* Mt_h = Mr_l + 2048 * D_;                // [4][768][512]     3 MB
  ushort* Mt_l = Mt_h + 2048 * D_;                //                   3 MB
  ushort* Wt_h = Mt_l + 2048 * D_;                // [256][768] bf16   .375
  ushort* Wt_l = Wt_h + 256 * D_;                 //                   .375

  k0_prep<<<864, 256, 0, stream>>>(M, W1, W2, Mr_h, Mr_l, Mt_h, Mt_l,
                                   Wt_h, Wt_l);
  k1_mfma<<<dim3(2048 / 32, 8), 256, 0, stream>>>(Mr_h, Mr_l, Wt_h, Wt_l,
                                                  b1, b2, w1e, w2e);
  k2_scores<<<(B_ * N_) / 8, 512, 0, stream>>>(w1e, w2e, mask, vw, ah, al);
  k3_mfma<<<dim3(2048 / 64, D_ / 32), 256, 0, stream>>>(ah, al, Mt_h, Mt_l,
                                                        out);
}